// Round 1
// baseline (155.936 us; speedup 1.0000x reference)
//
#include <hip/hip_runtime.h>
#include <math.h>

// Problem constants (match reference setup_inputs)
constexpr int Bn = 131072;   // batch
constexpr int Fn = 1024;     // features
constexpr int Tn = 100;      // trees
constexpr int Kn = 32;       // features per tree

constexpr int BLOCK = 256;
constexpr int WPB   = BLOCK / 64;   // waves per block = 4
constexpr int GRID  = 768;          // 3 blocks/CU * 256 CUs; 3072 waves, ~42-43 rows each

using gptr_t = const __attribute__((address_space(1))) void*;
using lptr_t = __attribute__((address_space(3))) void*;

__global__ __launch_bounds__(BLOCK)
void rf_fwd(const float* __restrict__ x,
            const int*   __restrict__ fidx,
            const float* __restrict__ fthr,
            const float* __restrict__ fw,
            float*       __restrict__ out)
{
    __shared__ float ldsbuf[WPB][2][Fn];   // 32 KB per block: per-wave double buffer

    const int lane  = threadIdx.x & 63;
    const int wid   = threadIdx.x >> 6;
    const int gwave = blockIdx.x * WPB + wid;
    const int nwave = GRID * WPB;

    // Lane handles tree t0 = lane, and t1 = 64+lane when it exists (lane < 36).
    const int  t0   = lane;
    const bool has1 = (64 + lane) < Tn;
    const int  t1   = has1 ? (64 + lane) : lane;   // fallback keeps loads in bounds

    // ---- Load per-lane (idx, w) tables into registers; compute bias ----
    int   off0[Kn]; float w0[Kn];
    int   off1[Kn]; float w1[Kn];
    float bias0 = 0.f, bias1 = 0.f;

#pragma unroll
    for (int k = 0; k < Kn; k += 4) {
        int4   i4 = *(const int4*)  (fidx + t0 * Kn + k);
        float4 wv = *(const float4*)(fw   + t0 * Kn + k);
        float4 th = *(const float4*)(fthr + t0 * Kn + k);
        off0[k+0] = i4.x; off0[k+1] = i4.y; off0[k+2] = i4.z; off0[k+3] = i4.w;
        w0[k+0] = wv.x; w0[k+1] = wv.y; w0[k+2] = wv.z; w0[k+3] = wv.w;
        bias0 += th.x*wv.x + th.y*wv.y + th.z*wv.z + th.w*wv.w;
    }
#pragma unroll
    for (int k = 0; k < Kn; k += 4) {
        int4   i4 = *(const int4*)  (fidx + t1 * Kn + k);
        float4 wv = *(const float4*)(fw   + t1 * Kn + k);
        float4 th = *(const float4*)(fthr + t1 * Kn + k);
        off1[k+0] = i4.x; off1[k+1] = i4.y; off1[k+2] = i4.z; off1[k+3] = i4.w;
        w1[k+0] = wv.x; w1[k+1] = wv.y; w1[k+2] = wv.z; w1[k+3] = wv.w;
        bias1 += th.x*wv.x + th.y*wv.y + th.z*wv.z + th.w*wv.w;
    }

    float* buf0 = &ldsbuf[wid][0][0];
    float* buf1 = &ldsbuf[wid][1][0];

    // Stage one 4KB row: 4 issues of 16B/lane (1KB each), wave-uniform LDS base,
    // per-lane global address. Linear dest order matches lane order (G21 ok).
    auto stage = [&](const float* src, float* dst) {
#pragma unroll
        for (int c = 0; c < 4; ++c) {
            __builtin_amdgcn_global_load_lds(
                (gptr_t)(src + c * 256 + lane * 4),
                (lptr_t)(dst + c * 256),
                16, 0, 0);
        }
    };

    int row = gwave;
    if (row < Bn) stage(x + (size_t)row * Fn, buf0);

    float* cur = buf0;
    float* nxt = buf1;

    for (; row < Bn; row += nwave) {
        const int nrow = row + nwave;          // wave-uniform
        if (nrow < Bn) {
            stage(x + (size_t)nrow * Fn, nxt);
            // FIFO: [4 cur-loads, (prev store), 4 next-loads] -> wait until only
            // the 4 newest (next-buf) remain: current buffer is complete.
            asm volatile("s_waitcnt vmcnt(4)" ::: "memory");
        } else {
            asm volatile("s_waitcnt vmcnt(0)" ::: "memory");
        }

        float acc0 = 0.f, acc1 = 0.f;
#pragma unroll
        for (int k = 0; k < Kn; ++k) {
            acc0 = fmaf(cur[off0[k]], w0[k], acc0);
            acc1 = fmaf(cur[off1[k]], w1[k], acc1);
        }

        const float ws0 = acc0 - bias0;
        const float ws1 = acc1 - bias1;
        const float p0  = 1.f / (1.f + __expf(-ws0));
        const float p1  = 1.f / (1.f + __expf(-ws1));

        float s = p0 + (has1 ? p1 : 0.f);
#pragma unroll
        for (int d = 1; d < 64; d <<= 1) s += __shfl_xor(s, d, 64);

        if (lane == 0) {
            const float pm = s * (1.0f / Tn);
            *(float2*)(out + (size_t)row * 2) = make_float2(1.0f - pm, pm);
        }

        float* tmp = cur; cur = nxt; nxt = tmp;
    }
}

extern "C" void kernel_launch(void* const* d_in, const int* in_sizes, int n_in,
                              void* d_out, int out_size, void* d_ws, size_t ws_size,
                              hipStream_t stream) {
    const float* x    = (const float*)d_in[0];
    const int*   fidx = (const int*)  d_in[1];
    const float* fthr = (const float*)d_in[2];
    const float* fw   = (const float*)d_in[3];
    float*       out  = (float*)d_out;

    rf_fwd<<<GRID, BLOCK, 0, stream>>>(x, fidx, fthr, fw, out);
}